// Round 1
// baseline (766.973 us; speedup 1.0000x reference)
//
#include <hip/hip_runtime.h>

typedef unsigned short ushort_t;
typedef short short8 __attribute__((ext_vector_type(8)));
typedef float f32x4 __attribute__((ext_vector_type(4)));

#define M_TOT 16384
#define N_TOT 4096
#define K_TOT 4096
#define R_LORA 16

// ---------------- helpers ----------------

__device__ __forceinline__ unsigned short f2bf(float f) {
  unsigned int u = __float_as_uint(f);
  unsigned int r = (u + 0x7fffu + ((u >> 16) & 1u)) >> 16;  // RNE
  return (unsigned short)r;
}

// async global->LDS, 16B per lane. LDS dest is wave-uniform base + lane*16.
__device__ __forceinline__ void gld_lds16(const void* g, void* l) {
  __builtin_amdgcn_global_load_lds(
      (__attribute__((address_space(1))) const unsigned int*)g,
      (__attribute__((address_space(3))) unsigned int*)l, 16, 0, 0);
}

// ---------------- fp32 -> bf16 convert ----------------

__global__ void cvt_bf16_kernel(const float* __restrict__ src,
                                ushort_t* __restrict__ dst, int n8) {
  for (long long i = (long long)blockIdx.x * 256 + threadIdx.x; i < n8;
       i += (long long)gridDim.x * 256) {
    const float4* s = (const float4*)src + i * 2;
    float4 a = s[0], b = s[1];
    union { ushort_t u[8]; uint4 v; } o;
    o.u[0] = f2bf(a.x); o.u[1] = f2bf(a.y); o.u[2] = f2bf(a.z); o.u[3] = f2bf(a.w);
    o.u[4] = f2bf(b.x); o.u[5] = f2bf(b.y); o.u[6] = f2bf(b.z); o.u[7] = f2bf(b.w);
    ((uint4*)dst)[i] = o.v;
  }
}

// ---------------- h[k][m][r] = sum_i x[k*1024+m][i] * A[k][r][i] (fp32) ----------------
// grid: 1024 blocks x 256 thr. Each wave owns 4 consecutive rows.

__global__ void lora_h_kernel(const float* __restrict__ x,
                              const float* __restrict__ lora_a,
                              float* __restrict__ h) {
  const int lane = threadIdx.x & 63;
  const int wave = threadIdx.x >> 6;
  const int rowBase = blockIdx.x * 16 + wave * 4;  // global row, 16 | 1024 so no group crossing
  const int g = rowBase >> 10;
  const float* A = lora_a + (size_t)g * R_LORA * K_TOT;

  float acc[4][16];
#pragma unroll
  for (int r = 0; r < 4; ++r)
#pragma unroll
    for (int t = 0; t < 16; ++t) acc[r][t] = 0.f;

  for (int i = lane; i < K_TOT; i += 64) {
    float xv[4];
#pragma unroll
    for (int r = 0; r < 4; ++r) xv[r] = x[(size_t)(rowBase + r) * K_TOT + i];
    float av[16];
#pragma unroll
    for (int t = 0; t < 16; ++t) av[t] = A[(size_t)t * K_TOT + i];
#pragma unroll
    for (int r = 0; r < 4; ++r)
#pragma unroll
      for (int t = 0; t < 16; ++t) acc[r][t] += xv[r] * av[t];
  }

#pragma unroll
  for (int r = 0; r < 4; ++r)
#pragma unroll
    for (int t = 0; t < 16; ++t) {
      float v = acc[r][t];
      v += __shfl_xor(v, 32); v += __shfl_xor(v, 16); v += __shfl_xor(v, 8);
      v += __shfl_xor(v, 4);  v += __shfl_xor(v, 2);  v += __shfl_xor(v, 1);
      if (lane == 0) {
        int mloc = (rowBase + r) & 1023;
        h[((size_t)g << 14) + (size_t)mloc * 16 + t] = v;
      }
    }
}

// ---------------- main GEMM: out = Xbf * Wbf^T + bias + h*lb^T ----------------
// 128x128 tile, BK=64, 4 waves (2x2), 16x16x32 bf16 MFMA, m97 2-barrier structure.
// LDS tiles XOR-swizzled: byte_in_row ^= (row&7)<<4 (read side); staging uses
// linear LDS dest + inverse-swizzled per-lane GLOBAL source (m173/m201 pattern).

__global__ __launch_bounds__(256, 3) void gemm_kernel(
    const ushort_t* __restrict__ xb,    // [M][K] bf16
    const ushort_t* __restrict__ wb,    // [N][K] bf16 (B^T form)
    const float* __restrict__ bias,     // [N]
    const float* __restrict__ hbuf,     // [16][1024][16] fp32
    const float* __restrict__ lorab,    // [16][4096][16] fp32
    float* __restrict__ out) {          // [M][N] fp32
  __shared__ __align__(16) ushort_t lds[16384];  // A: [0,8192) elems, B: [8192,16384)

  const int tid = threadIdx.x;
  const int lane = tid & 63;
  const int wave = tid >> 6;
  const int wm = wave >> 1, wn = wave & 1;
  const int bx = blockIdx.x;            // col tile 0..31
  const int by = blockIdx.y;            // row tile 0..127
  const int rowBase = by * 128;
  const int colBase = bx * 128;

  // staging geometry: chunk c (1KB) covers tile rows c*8 .. c*8+7.
  // lane l -> row c*8 + (l>>3), LDS in-row byte (l&7)*16.
  // inverse-swizzled source column (elements): ((l&7) ^ (l>>3)) * 8
  const int srow = lane >> 3;
  const int scol = ((lane & 7) ^ srow) << 3;

  const ushort_t* aSrc[4];
  const ushort_t* bSrc[4];
#pragma unroll
  for (int j = 0; j < 4; ++j) {
    int c = wave * 4 + j;
    aSrc[j] = xb + (size_t)(rowBase + c * 8 + srow) * K_TOT + scol;
    bSrc[j] = wb + (size_t)(colBase + c * 8 + srow) * K_TOT + scol;
  }

  f32x4 acc[4][4] = {};

  const int fr = lane & 15;   // fragment row (m or n)
  const int fg = lane >> 4;   // k-group: k = 8*fg .. 8*fg+7

  for (int kt = 0; kt < K_TOT / 64; ++kt) {
    const int kofs = kt * 64;
#pragma unroll
    for (int j = 0; j < 4; ++j) {
      int c = wave * 4 + j;
      gld_lds16(aSrc[j] + kofs, &lds[c * 512]);
      gld_lds16(bSrc[j] + kofs, &lds[8192 + c * 512]);
    }
    __syncthreads();   // compiler drains vmcnt(0) before s_barrier

#pragma unroll
    for (int kk = 0; kk < 2; ++kk) {
      short8 afr[4], bfr[4];
#pragma unroll
      for (int mt = 0; mt < 4; ++mt) {
        int row = wm * 64 + mt * 16 + fr;
        int inrow = kk * 64 + 16 * fg;               // bytes within 128B row
        int off = row * 128 + (inrow ^ ((row & 7) << 4));
        afr[mt] = *(const short8*)((const char*)lds + off);
      }
#pragma unroll
      for (int nt = 0; nt < 4; ++nt) {
        int row = wn * 64 + nt * 16 + fr;
        int inrow = kk * 64 + 16 * fg;
        int off = row * 128 + (inrow ^ ((row & 7) << 4));
        bfr[nt] = *(const short8*)((const char*)lds + 16384 + off);
      }
#pragma unroll
      for (int mt = 0; mt < 4; ++mt)
#pragma unroll
        for (int nt = 0; nt < 4; ++nt)
          acc[mt][nt] = __builtin_amdgcn_mfma_f32_16x16x32_bf16(
              afr[mt], bfr[nt], acc[mt][nt], 0, 0, 0);
    }
    __syncthreads();   // protect LDS before next stage overwrites
  }

  // ---------- epilogue: bias + LoRA delta, fused ----------
  float* hs = (float*)lds;        // h tile  [128][16] fp32 (8KB)
  float* lbs = hs + 2048;         // lb tile [128][16] fp32 (8KB)
  {
    const int g = by >> 3;
    const float* hsrc = hbuf + (((size_t)g * 1024 + (size_t)(by & 7) * 128) * 16);
    const float* lsrc = lorab + (((size_t)g * 4096 + (size_t)colBase) * 16);
    for (int idx = tid; idx < 512; idx += 256) {
      ((float4*)hs)[idx] = ((const float4*)hsrc)[idx];
      ((float4*)lbs)[idx] = ((const float4*)lsrc)[idx];
    }
  }
  __syncthreads();

  float lbv[4][16];
  float bv[4];
#pragma unroll
  for (int nt = 0; nt < 4; ++nt) {
    int cl = wn * 64 + nt * 16 + fr;
    bv[nt] = bias[colBase + cl];
#pragma unroll
    for (int r = 0; r < 16; ++r) lbv[nt][r] = lbs[cl * 16 + r];
  }

#pragma unroll
  for (int mt = 0; mt < 4; ++mt) {
#pragma unroll
    for (int i = 0; i < 4; ++i) {
      int rl = wm * 64 + mt * 16 + 4 * fg + i;
      float hv[16];
#pragma unroll
      for (int r = 0; r < 16; ++r) hv[r] = hs[rl * 16 + r];
      float* orow = out + (size_t)(rowBase + rl) * N_TOT + colBase;
#pragma unroll
      for (int nt = 0; nt < 4; ++nt) {
        float d = 0.f;
#pragma unroll
        for (int r = 0; r < 16; ++r) d += hv[r] * lbv[nt][r];
        orow[wn * 64 + nt * 16 + fr] = acc[mt][nt][i] + bv[nt] + d;
      }
    }
  }
}

// ---------------- launch ----------------

extern "C" void kernel_launch(void* const* d_in, const int* in_sizes, int n_in,
                              void* d_out, int out_size, void* d_ws, size_t ws_size,
                              hipStream_t stream) {
  const float* x      = (const float*)d_in[0];  // [16384][4096]
  const float* base_w = (const float*)d_in[1];  // [4096][4096]
  const float* base_b = (const float*)d_in[2];  // [4096]
  const float* lora_a = (const float*)d_in[3];  // [16][16][4096]
  const float* lora_b = (const float*)d_in[4];  // [16][4096][16]
  float* out = (float*)d_out;

  // workspace layout: h (1MB) | w_bf16 (32MB) | x_bf16 (128MB)  => 161MB
  char* ws = (char*)d_ws;
  float* h = (float*)ws;
  ushort_t* wb = (ushort_t*)(ws + (1u << 20));
  ushort_t* xb = (ushort_t*)(ws + (1u << 20) + (32u << 20));

  cvt_bf16_kernel<<<4096, 256, 0, stream>>>(x, xb, (M_TOT * K_TOT) / 8);
  cvt_bf16_kernel<<<2048, 256, 0, stream>>>(base_w, wb, (N_TOT * K_TOT) / 8);
  lora_h_kernel<<<M_TOT / 16, 256, 0, stream>>>(x, lora_a, h);
  gemm_kernel<<<dim3(N_TOT / 128, M_TOT / 128), 256, 0, stream>>>(
      xb, wb, base_b, h, lora_b, out);
}